// Round 13
// baseline (155.031 us; speedup 1.0000x reference)
//
#include <hip/hip_runtime.h>
#include <hip/hip_fp16.h>

// CropRoi: 3D adaptive max-pool over per-proposal crop boxes.
// f:        [B=4, C=64, 24, 24, 24] f32
// proposals:[N, 8] f32 = [b, score, cx, cy, cz, sx, sy, sz]
// out:      [N, C, 7, 7, 7] f32
//
// r12: SINGLE dispatch, producer->consumer flag (NOT grid.sync — r9 showed
// grid.sync ~100us). Blocks 0..863 = r11 transpose tiles; blocks 864..2207 =
// r11 compute blocks. Producers release-increment a counter in d_ws after
// device-scope fence; consumers acquire-spin until 864 then run verbatim
// r11 compute. Deadlock-free: producers never wait; any resident set makes
// progress (capacity 2048 >= producers; retiring blocks admit the rest).
// Counter zeroed per call via hipMemsetAsync node (deterministic).
// ft contents are replay-invariant, so even a stale-cache read would be
// byte-identical; acquire/release + end-of-dispatch L2 flushes close the
// first-call case.
//
// History: r8 predication -3.1us (TA); r10 z=1 regressed (latency, low TLP);
// r11 8binx8lane flat (-0.35) => residual is the dispatch boundary (theory
// under test here).
// Precision: fp16 RTN on ~N(0,1); absmax 0.03125 << 0.099 (r5/r7/r8/r10/r11).

#define SS 7
#define CC 64
#define DP 24
#define DP2 (DP*DP)        // 576
#define VOL (DP*DP*DP)     // 13824
#define INV_SCALE 0.25f
#define NEGINF2 0xFC00FC00u
#define NPROD 864          // transpose tile blocks
#define FT_BYTES ((size_t)4 * VOL * CC * 2)   // 7,077,888

static __device__ __forceinline__ unsigned pkmax(unsigned a, unsigned b) {
    unsigned r;
    asm("v_pk_max_f16 %0, %1, %2" : "=v"(r) : "v"(a), "v"(b));
    return r;
}

// ================= fused single-dispatch kernel =================
__global__ __launch_bounds__(256) void croproi_fused(
    const float* __restrict__ f,      // [B][CC][VOL] f32
    const float* __restrict__ props,  // [N][8]
    __half* __restrict__ ft,          // [B][VOL][CC] fp16 (d_ws)
    unsigned* __restrict__ cnt,       // d_ws + FT_BYTES, zeroed per call
    float* __restrict__ out)          // [N][CC][343] f32
{
    __shared__ float smem[64 * 65];   // producer tile / consumer ob (8.7KB)

    const int bid = blockIdx.x;

    if (bid < NPROD) {
        // ---------------- producer: transpose tile (r11 body) ----------------
        uint4* ft4 = (uint4*)ft;
        const int b  = bid / 216;
        const int s0 = (bid - b * 216) * 64;
        const int g16 = threadIdx.x >> 4;
        const int x4  = (threadIdx.x & 15) * 4;
        #pragma unroll
        for (int it = 0; it < 4; ++it) {
            const int r = it * 16 + g16;           // channel
            const float4 v = *(const float4*)&f[(size_t)(b * CC + r) * VOL + s0 + x4];
            smem[r * 65 + x4 + 0] = v.x; smem[r * 65 + x4 + 1] = v.y;
            smem[r * 65 + x4 + 2] = v.z; smem[r * 65 + x4 + 3] = v.w;
        }
        __syncthreads();
        const int c8 = (threadIdx.x & 7) * 8;
        #pragma unroll
        for (int it = 0; it < 2; ++it) {
            const int s = it * 32 + (threadIdx.x >> 3);
            __half h[8];
            #pragma unroll
            for (int u = 0; u < 8; ++u)
                h[u] = __float2half(smem[(c8 + u) * 65 + s]);
            ft4[((size_t)b * VOL + s0 + s) * (CC / 8) + (c8 >> 3)] = *(uint4*)h;
        }
        __threadfence();               // per-wave device-scope release of stores
        __syncthreads();               // all waves' fences complete
        if (threadIdx.x == 0)
            __hip_atomic_fetch_add(cnt, 1u, __ATOMIC_RELEASE,
                                   __HIP_MEMORY_SCOPE_AGENT);
        return;
    }

    // ---------------- consumer: wait for all producers ----------------
    if (threadIdx.x == 0) {
        while (__hip_atomic_load(cnt, __ATOMIC_ACQUIRE,
                                 __HIP_MEMORY_SCOPE_AGENT) < NPROD)
            __builtin_amdgcn_s_sleep(8);
    }
    __syncthreads();

    // ---------------- consumer: bin compute (r11 body verbatim) -------
    const int cid  = bid - NPROD;             // 0..1343
    const int n    = cid % 96;                // cid%8 == n%8: XCD locality kept
    const int iq   = cid / 96;                // 0..13
    const int i    = iq % SS;                 // z-bin slice
    const int zq   = iq / SS;                 // bin-half (0: 32 bins, 1: 17)
    const int w    = threadIdx.x >> 6;
    const int lane = threadIdx.x & 63;
    const int o8   = lane >> 3;               // bin within oct (0..7)
    const int lc8  = lane & 7;                // channel octet (8 fp16 = 16 B)

    const float* p = props + (size_t)n * 8;
    int b = (int)p[0];

    int lo0, lo1, lo2, L0, L1, L2;
    {
        float c0f = p[2] - 0.5f * p[5];
        float c1f = c0f + p[5];
        int lo = (int)floorf(c0f * INV_SCALE); if (lo < 0) lo = 0;
        int hi = (int)ceilf (c1f * INV_SCALE); if (hi > DP) hi = DP;
        lo0 = lo; L0 = hi - lo;

        c0f = p[3] - 0.5f * p[6];
        c1f = c0f + p[6];
        lo = (int)floorf(c0f * INV_SCALE); if (lo < 0) lo = 0;
        hi = (int)ceilf (c1f * INV_SCALE); if (hi > DP) hi = DP;
        lo1 = lo; L1 = hi - lo;

        c0f = p[4] - 0.5f * p[7];
        c1f = c0f + p[7];
        lo = (int)floorf(c0f * INV_SCALE); if (lo < 0) lo = 0;
        hi = (int)ceilf (c1f * INV_SCALE); if (hi > DP) hi = DP;
        lo2 = lo; L2 = hi - lo;
    }
    b   = __builtin_amdgcn_readfirstlane(b);
    lo0 = __builtin_amdgcn_readfirstlane(lo0);
    lo1 = __builtin_amdgcn_readfirstlane(lo1);
    lo2 = __builtin_amdgcn_readfirstlane(lo2);
    L0  = __builtin_amdgcn_readfirstlane(L0);
    L1  = __builtin_amdgcn_readfirstlane(L1);
    L2  = __builtin_amdgcn_readfirstlane(L2);

    const int zs = (i * L0) / SS;
    const int ez = ((i + 1) * L0 + SS - 1) / SS - zs;        // 1..3

    const uint4* base0 = (const uint4*)(ft
        + ((size_t)b * VOL + (size_t)(lo0 + zs) * DP2
           + (size_t)lo1 * DP + lo2) * CC);

    const int olo = zq * 4;
    const int ohi = (olo + 4 < 7) ? olo + 4 : 7;
    const int binbase = zq * 32;
    float* ob = smem;                          // [32*68] region

    for (int oct = olo + w; oct < ohi; oct += 4) {   // exactly 0 or 1 iter
        const int jkr = oct * 8 + o8;
        const bool valid = (jkr <= 48);
        const int jk = valid ? jkr : 48;
        const int j  = jk / SS;
        const int k  = jk - j * SS;
        const int ys = (j * L1) / SS;
        const int ey = ((j + 1) * L1 + SS - 1) / SS - ys;    // 1..3
        const int xs = (k * L2) / SS;
        const int ex = ((k + 1) * L2 + SS - 1) / SS - xs;    // 1..3

        uint4 vv[27];
        #pragma unroll
        for (int q = 0; q < 27; ++q) {
            vv[q].x = NEGINF2; vv[q].y = NEGINF2;
            vv[q].z = NEGINF2; vv[q].w = NEGINF2;
        }

        #pragma unroll
        for (int zi = 0; zi < 3; ++zi) {
            if (zi < ez) {                               // wave-uniform
                const uint4* pz = base0 + zi * (DP2 * 8);
                #pragma unroll
                for (int yi = 0; yi < 3; ++yi) {
                    #pragma unroll
                    for (int xi = 0; xi < 3; ++xi) {
                        if (yi < ey && xi < ex)          // per-lane exec mask
                            vv[zi * 9 + yi * 3 + xi] =
                                pz[(ys + yi) * (DP * 8) + (xs + xi) * 8 + lc8];
                    }
                }
            }
        }

        unsigned m0 = NEGINF2, m1 = NEGINF2, m2 = NEGINF2, m3 = NEGINF2;
        #pragma unroll
        for (int q = 0; q < 27; ++q) {
            m0 = pkmax(m0, vv[q].x);
            m1 = pkmax(m1, vv[q].y);
            m2 = pkmax(m2, vv[q].z);
            m3 = pkmax(m3, vv[q].w);
        }

        if (valid) {
            const __half2 h0 = *(const __half2*)&m0;
            const __half2 h1 = *(const __half2*)&m1;
            const __half2 h2 = *(const __half2*)&m2;
            const __half2 h3 = *(const __half2*)&m3;
            float4 fa, fb4;
            fa.x  = __half2float(h0.x); fa.y  = __half2float(h0.y);
            fa.z  = __half2float(h1.x); fa.w  = __half2float(h1.y);
            fb4.x = __half2float(h2.x); fb4.y = __half2float(h2.y);
            fb4.z = __half2float(h3.x); fb4.w = __half2float(h3.y);
            float* row = &ob[(jk - binbase) * 68 + lc8 * 8];
            *(float4*)row       = fa;
            *(float4*)(row + 4) = fb4;
        }
    }
    __syncthreads();

    float* op = out + (size_t)n * CC * (SS * SS * SS) + (size_t)i * 49 + binbase;
    if (zq == 0) {
        for (int idx = threadIdx.x; idx < 32 * CC; idx += 256) {
            const int c = idx >> 5;
            const int q = idx & 31;
            op[(size_t)c * 343 + q] = ob[q * 68 + c];
        }
    } else {
        for (int idx = threadIdx.x; idx < 17 * CC; idx += 256) {
            const int c = idx / 17;
            const int q = idx - c * 17;
            op[(size_t)c * 343 + q] = ob[q * 68 + c];
        }
    }
}

// ---------------- fallback: round-0 thread-per-bin (proven) --------
__global__ __launch_bounds__(256) void croproi_fallback(
    const float* __restrict__ f, const float* __restrict__ props,
    float* __restrict__ out, int total)
{
    int tid = blockIdx.x * blockDim.x + threadIdx.x;
    if (tid >= total) return;
    int k = tid % SS;
    int t = tid / SS;
    int j = t % SS; t /= SS;
    int i = t % SS; t /= SS;
    int c = t % CC;
    int n = t / CC;
    const float* p = props + n * 8;
    int b = (int)p[0];
    int lo0, lo1, lo2, L0, L1, L2;
    {
        float c0f = p[2] - 0.5f * p[5]; float c1f = c0f + p[5];
        int lo = (int)floorf(c0f * INV_SCALE); if (lo < 0) lo = 0;
        int hi = (int)ceilf (c1f * INV_SCALE); if (hi > DP) hi = DP;
        lo0 = lo; L0 = hi - lo;
        c0f = p[3] - 0.5f * p[6]; c1f = c0f + p[6];
        lo = (int)floorf(c0f * INV_SCALE); if (lo < 0) lo = 0;
        hi = (int)ceilf (c1f * INV_SCALE); if (hi > DP) hi = DP;
        lo1 = lo; L1 = hi - lo;
        c0f = p[4] - 0.5f * p[7]; c1f = c0f + p[7];
        lo = (int)floorf(c0f * INV_SCALE); if (lo < 0) lo = 0;
        hi = (int)ceilf (c1f * INV_SCALE); if (hi > DP) hi = DP;
        lo2 = lo; L2 = hi - lo;
    }
    int zs = lo0 + (i * L0) / SS, ze = lo0 + ((i + 1) * L0 + SS - 1) / SS;
    int ys = lo1 + (j * L1) / SS, ye = lo1 + ((j + 1) * L1 + SS - 1) / SS;
    int xs = lo2 + (k * L2) / SS, xe = lo2 + ((k + 1) * L2 + SS - 1) / SS;
    const float* fb = f + (size_t)(b * CC + c) * VOL;
    float m = -INFINITY;
    for (int z = zs; z < ze; ++z)
        for (int y = ys; y < ye; ++y) {
            const float* row = fb + (z * DP + y) * DP;
            for (int x = xs; x < xe; ++x) m = fmaxf(m, row[x]);
        }
    out[tid] = m;
}

extern "C" void kernel_launch(void* const* d_in, const int* in_sizes, int n_in,
                              void* d_out, int out_size, void* d_ws, size_t ws_size,
                              hipStream_t stream) {
    const float* f     = (const float*)d_in[0];
    const float* props = (const float*)d_in[2];
    float* out = (float*)d_out;

    const int B = in_sizes[0] / (CC * VOL);   // 4
    const int N = in_sizes[2] / 8;            // 96

    if (B == 4 && N == 96 && ws_size >= FT_BYTES + 64) {
        __half* ft = (__half*)d_ws;
        unsigned* cnt = (unsigned*)((char*)d_ws + FT_BYTES);
        hipMemsetAsync((void*)cnt, 0, 4, stream);          // graph memset node
        const int nblocks = NPROD + 96 * SS * 2;           // 864 + 1344 = 2208
        croproi_fused<<<nblocks, 256, 0, stream>>>(f, props, ft, cnt, out);
    } else {
        int total = N * CC * SS * SS * SS;
        croproi_fallback<<<(total + 255) / 256, 256, 0, stream>>>(f, props, out, total);
    }
}

// Round 14
// 52.791 us; speedup vs baseline: 2.9367x; 2.9367x over previous
//
#include <hip/hip_runtime.h>

// CropRoi: 3D adaptive max-pool over per-proposal crop boxes — SINGLE
// direct kernel, no intermediate, no workspace, exact f32.
// f:        [B=4, C=64, 24, 24, 24] f32
// proposals:[N, 8] f32 = [b, score, cx, cy, cz, sx, sy, sz]
// out:      [N, C, 7, 7, 7] f32
//
// Block = (n, channel-group of 4). Grid (96, 16) = 1536 blocks; bid%8 = n%8
// so all blocks of a proposal share an XCD (L2 reuse across c-groups' f reads
// is nil anyway, but n-locality helps overlapping proposals).
//
// Phase 1 (staging): per (cl, z) the crop y-slab is CONTIGUOUS in f:
//   words [slabrel, slabrel+LEN), LEN = (L1-1)*24 + L2 <= 301. Load as
//   aligned float4 (coalesced), strip slop via compile-time /24, store dense
//   LDS crop[cl][z][y][x] (strides 2197/169/13). Last-float4 edge handled
//   with a scalar-guarded path (OOB past f's end only).
// Phase 2 (pool): thread = (cl, lane); lane sweeps bins; per bin max over
//   ez*ey*ex <= 27 LDS words (runtime loops, exec-masked; max trip ~2.5^3).
// Phase 3: obuf staged, flat coalesced 5.5 KB store per block.
//
// LDS = 4*2197*4 + 4*343*4 = 40,640 B -> 4 blocks/CU (163,840 exactly).
//
// History: r9 grid.sync ~100us; r12 producer-consumer flag ~155us — ANY
// intra-dispatch cross-XCD sync is ~100us on MI355X. r2/r6 (earlier fused
// tries) died on serial scalar staging + shfl pooling, both fixed here.
// Box semantics identical rounds 0-12; f32 exact -> absmax 0 expected.

#define SS 7
#define CC 64
#define DP 24
#define DP2 (DP*DP)        // 576
#define VOL (DP*DP*DP)     // 13824
#define INV_SCALE 0.25f
#define CPB 4              // channels per block
#define CSTR 2197          // 13^3 crop stride per channel (words)
#define ZSTR 169           // 13^2
#define YSTR 13

__global__ __launch_bounds__(256) void croproi_direct(
    const float* __restrict__ f,      // [B][CC][VOL] f32
    const float* __restrict__ props,  // [N][8]
    float* __restrict__ out,          // [N][CC][343] f32
    int totwords)                     // B*CC*VOL
{
    __shared__ float crop[CPB * CSTR];   // 35,152 B
    __shared__ float obuf[CPB * 343];    //  5,488 B

    const int n  = blockIdx.x;
    const int c0 = blockIdx.y * CPB;
    const int t  = threadIdx.x;

    // ---- box decode (wave-uniform -> SGPR) ----
    const float* p = props + (size_t)n * 8;
    int b = (int)p[0];
    int lo0, lo1, lo2, L0, L1, L2;
    {
        float c0f = p[2] - 0.5f * p[5];
        float c1f = c0f + p[5];
        int lo = (int)floorf(c0f * INV_SCALE); if (lo < 0) lo = 0;
        int hi = (int)ceilf (c1f * INV_SCALE); if (hi > DP) hi = DP;
        lo0 = lo; L0 = hi - lo;

        c0f = p[3] - 0.5f * p[6];
        c1f = c0f + p[6];
        lo = (int)floorf(c0f * INV_SCALE); if (lo < 0) lo = 0;
        hi = (int)ceilf (c1f * INV_SCALE); if (hi > DP) hi = DP;
        lo1 = lo; L1 = hi - lo;

        c0f = p[4] - 0.5f * p[7];
        c1f = c0f + p[7];
        lo = (int)floorf(c0f * INV_SCALE); if (lo < 0) lo = 0;
        hi = (int)ceilf (c1f * INV_SCALE); if (hi > DP) hi = DP;
        lo2 = lo; L2 = hi - lo;
    }
    b   = __builtin_amdgcn_readfirstlane(b);
    lo0 = __builtin_amdgcn_readfirstlane(lo0);
    lo1 = __builtin_amdgcn_readfirstlane(lo1);
    lo2 = __builtin_amdgcn_readfirstlane(lo2);
    L0  = __builtin_amdgcn_readfirstlane(L0);
    L1  = __builtin_amdgcn_readfirstlane(L1);
    L2  = __builtin_amdgcn_readfirstlane(L2);

    // ---- phase 1: coalesced slop-tolerant staging ----
    const int slabrel = lo1 * DP + lo2;          // crop origin within z-plane
    const int al0     = slabrel & ~3;            // float4-aligned start
    const int LEN     = (L1 - 1) * DP + L2;      // contiguous span (words)
    const int F4      = ((slabrel - al0) + LEN + 3) >> 2;   // float4s per (cl,z)
    const int work    = CPB * L0 * F4;           // <= 4*13*76 = 3952

    for (int it = t; it < work; it += 256) {
        const int cz = it / F4;                  // runtime div (uniform divisor)
        const int f4 = it - cz * F4;
        const int cl = cz / L0;
        const int z  = cz - cl * L0;
        const int w0 = al0 + 4 * f4;             // z-plane-relative word
        const int gi = (b * CC + c0 + cl) * VOL + (lo0 + z) * DP2 + w0;

        float4 v;
        if (gi + 3 < totwords) {
            v = *(const float4*)&f[gi];
        } else {                                  // only at the very end of f
            float* vw = (float*)&v;
            #pragma unroll
            for (int u = 0; u < 4; ++u)
                vw[u] = (gi + u < totwords) ? f[gi + u] : 0.0f;
        }

        const float* vw = (const float*)&v;
        #pragma unroll
        for (int u = 0; u < 4; ++u) {
            const int ww = w0 + u - slabrel;     // crop-slab-relative word
            if (ww >= 0) {
                const int y = ww / DP;           // DP=24: compile-time magic
                const int x = ww - y * DP;
                if (y < L1 && x < L2)            // strip slop / leading pad
                    crop[cl * CSTR + z * ZSTR + y * YSTR + x] = vw[u];
            }
        }
    }
    __syncthreads();

    // ---- phase 2: thread-per-bin pooling from LDS ----
    const int cl   = t >> 6;
    const int lane = t & 63;
    const float* cb = &crop[cl * CSTR];
    for (int bb = lane; bb < 343; bb += 64) {
        const int i = bb / 49;                   // compile-time divisors
        const int r = bb - i * 49;
        const int j = r / SS;
        const int k = r - j * SS;
        const int zs = (i * L0) / SS, ez = ((i + 1) * L0 + 6) / SS - zs;
        const int ys = (j * L1) / SS, ey = ((j + 1) * L1 + 6) / SS - ys;
        const int xs = (k * L2) / SS, ex = ((k + 1) * L2 + 6) / SS - xs;

        float m = -INFINITY;
        for (int zi = 0; zi < ez; ++zi) {
            const float* zb = cb + (zs + zi) * ZSTR + ys * YSTR + xs;
            for (int yi = 0; yi < ey; ++yi) {
                const float* row = zb + yi * YSTR;
                for (int xi = 0; xi < ex; ++xi)
                    m = fmaxf(m, row[xi]);
            }
        }
        obuf[cl * 343 + bb] = m;
    }
    __syncthreads();

    // ---- phase 3: coalesced write-out (4 channels x 343 contiguous) ----
    float* op = out + ((size_t)n * CC + c0) * 343;
    for (int idx = t; idx < CPB * 343; idx += 256)
        op[idx] = obuf[idx];
}

extern "C" void kernel_launch(void* const* d_in, const int* in_sizes, int n_in,
                              void* d_out, int out_size, void* d_ws, size_t ws_size,
                              hipStream_t stream) {
    const float* f     = (const float*)d_in[0];
    const float* props = (const float*)d_in[2];
    float* out = (float*)d_out;

    const int N = in_sizes[2] / 8;            // 96
    const int totwords = in_sizes[0];         // B*CC*VOL

    dim3 grid(N, CC / CPB);                   // 96 x 16 = 1536 blocks
    croproi_direct<<<grid, 256, 0, stream>>>(f, props, out, totwords);
}

// Round 15
// 18.532 us; speedup vs baseline: 8.3655x; 2.8486x over previous
//
#include <hip/hip_runtime.h>
#include <hip/hip_fp16.h>

// CropRoi: 3D adaptive max-pool over per-proposal crop boxes.
// f:        [B=4, C=64, 24, 24, 24] f32
// proposals:[N, 8] f32 = [b, score, cx, cy, cz, sx, sy, sz]
// out:      [N, C, 7, 7, 7] f32
//
// K1 (unchanged, proven): transpose+fp16 f -> ft[b][s][c] channel-last.
// K2 (r14 NEW): separable STREAMING pool, block=(n,i), grid 96x7:
//   Phase A: unit (j,x,c8); lanes sweep c8-then-x -> each load inst reads
//     up to 1KB CONTIGUOUS ft; zy-pool via <=9 exact-predicated loads
//     (r8 pattern) into LDS P[7][13][8] uint4. Each line read once,
//     sequentially (~37KB/block vs ~73KB scattered in r11's gather).
//   Phase B: x-pool: <=3 ds_read_b128 from P per (j,k,c8), unpack->f32 obuf.
//   Phase C: r11's coalesced 49-run writeout.
//   LDS 25KB; no serial chains; 2 syncthreads.
//
// History: r9 grid.sync / r12 pc-flag ~100-155us (intra-dispatch cross-XCD
// sync dead); r13 direct kernel 52.8us (LDS-chain pooling dead); r8
// predication -3.1us (line-service is K2's cost -> this round streams it).
// Precision: fp16 RTN on ~N(0,1); absmax 0.03125 << 0.099.

#define SS 7
#define CC 64
#define DP 24
#define DP2 (DP*DP)        // 576
#define VOL (DP*DP*DP)     // 13824
#define INV_SCALE 0.25f
#define NEGINF2 0xFC00FC00u

static __device__ __forceinline__ unsigned pkmax(unsigned a, unsigned b) {
    unsigned r;
    asm("v_pk_max_f16 %0, %1, %2" : "=v"(r) : "v"(a), "v"(b));
    return r;
}
static __device__ __forceinline__ uint4 pkmax4(uint4 a, uint4 b) {
    uint4 r;
    r.x = pkmax(a.x, b.x); r.y = pkmax(a.y, b.y);
    r.z = pkmax(a.z, b.z); r.w = pkmax(a.w, b.w);
    return r;
}

// ---------------- kernel 1: channel-last transpose to fp16 (r8 body) -------
__global__ __launch_bounds__(256) void transpose_cl(
    const float* __restrict__ f,   // [B][CC][VOL] f32
    uint4* __restrict__ ft4)       // [B][VOL][CC/8]
{
    __shared__ float tile[64][65];
    const int b  = blockIdx.y;
    const int s0 = blockIdx.x * 64;
    const int g16 = threadIdx.x >> 4;
    const int x4  = (threadIdx.x & 15) * 4;
    #pragma unroll
    for (int it = 0; it < 4; ++it) {
        const int r = it * 16 + g16;           // channel
        const float4 v = *(const float4*)&f[(size_t)(b * CC + r) * VOL + s0 + x4];
        tile[r][x4 + 0] = v.x; tile[r][x4 + 1] = v.y;
        tile[r][x4 + 2] = v.z; tile[r][x4 + 3] = v.w;
    }
    __syncthreads();
    const int c8 = (threadIdx.x & 7) * 8;
    #pragma unroll
    for (int it = 0; it < 2; ++it) {
        const int s = it * 32 + (threadIdx.x >> 3);
        __half h[8];
        #pragma unroll
        for (int u = 0; u < 8; ++u)
            h[u] = __float2half(tile[c8 + u][s]);   // 2-way bank alias: free
        ft4[((size_t)b * VOL + s0 + s) * (CC / 8) + (c8 >> 3)] = *(uint4*)h;
    }
}

// ---------------- kernel 2: separable streaming pool ----------------
__global__ __launch_bounds__(256) void croproi_stream(
    const __half* __restrict__ ft,    // [B][VOL][CC] fp16
    const float* __restrict__ props,  // [N][8]
    float* __restrict__ out)          // [N][CC][343] f32
{
    __shared__ uint4 P[7 * 104];      // [j][x(13)][c8(8)]  11,648 B
    __shared__ float obuf[49 * 68];   // 13,328 B
    const int n = blockIdx.x;
    const int i = blockIdx.y;         // z-bin slice
    const int t = threadIdx.x;

    // ---- box decode (wave-uniform -> SGPR) ----
    const float* p = props + (size_t)n * 8;
    int b = (int)p[0];
    int lo0, lo1, lo2, L0, L1, L2;
    {
        float c0f = p[2] - 0.5f * p[5];
        float c1f = c0f + p[5];
        int lo = (int)floorf(c0f * INV_SCALE); if (lo < 0) lo = 0;
        int hi = (int)ceilf (c1f * INV_SCALE); if (hi > DP) hi = DP;
        lo0 = lo; L0 = hi - lo;

        c0f = p[3] - 0.5f * p[6];
        c1f = c0f + p[6];
        lo = (int)floorf(c0f * INV_SCALE); if (lo < 0) lo = 0;
        hi = (int)ceilf (c1f * INV_SCALE); if (hi > DP) hi = DP;
        lo1 = lo; L1 = hi - lo;

        c0f = p[4] - 0.5f * p[7];
        c1f = c0f + p[7];
        lo = (int)floorf(c0f * INV_SCALE); if (lo < 0) lo = 0;
        hi = (int)ceilf (c1f * INV_SCALE); if (hi > DP) hi = DP;
        lo2 = lo; L2 = hi - lo;
    }
    b   = __builtin_amdgcn_readfirstlane(b);
    lo0 = __builtin_amdgcn_readfirstlane(lo0);
    lo1 = __builtin_amdgcn_readfirstlane(lo1);
    lo2 = __builtin_amdgcn_readfirstlane(lo2);
    L0  = __builtin_amdgcn_readfirstlane(L0);
    L1  = __builtin_amdgcn_readfirstlane(L1);
    L2  = __builtin_amdgcn_readfirstlane(L2);

    const int zs = (i * L0) / SS;
    const int ez = ((i + 1) * L0 + 6) / SS - zs;        // 1..3 (uniform)

    // base at (b, lo0+zs, lo1, lo2), channel 0, in uint4 units (8/point)
    const uint4* base0 = (const uint4*)ft
        + ((size_t)b * VOL + (size_t)(lo0 + zs) * DP2
           + (size_t)lo1 * DP + lo2) * 8;

    // ---- phase A: zy-pool streaming loads -> P[j][x][c8] ----
    // units: 7j * 13x * 8c8 = 728; lanes sweep c8 then x => contiguous loads
    for (int u = t; u < 728; u += 256) {
        const int j  = u / 104;                 // const-divisor magic
        const int r  = u - j * 104;
        const int x  = r >> 3;
        const int c8 = r & 7;
        const int ys = (j * L1) / SS;
        const int ey = ((j + 1) * L1 + 6) / SS - ys;     // 1..3
        const bool act = (x < L2);

        const uint4* bp = base0 + (ys * DP + x) * 8 + c8;
        uint4 m; m.x = m.y = m.z = m.w = NEGINF2;
        #pragma unroll
        for (int zi = 0; zi < 3; ++zi) {
            if (zi < ez) {                      // wave-uniform branch
                const uint4* bz = bp + zi * (DP2 * 8);
                uint4 v0, v1, v2;
                v0.x = v0.y = v0.z = v0.w = NEGINF2; v1 = v0; v2 = v0;
                if (act)           v0 = bz[0];           // exec-masked
                if (act && ey > 1) v1 = bz[DP * 8];
                if (act && ey > 2) v2 = bz[2 * DP * 8];
                m = pkmax4(m, pkmax4(pkmax4(v0, v1), v2));
            }
        }
        if (act) P[j * 104 + x * 8 + c8] = m;
    }
    __syncthreads();

    // ---- phase B: x-pool from P -> obuf f32 ----
    // units: 49jk * 8c8 = 392
    for (int u = t; u < 392; u += 256) {
        const int jk = u >> 3;
        const int c8 = u & 7;
        const int j  = jk / SS;                 // const-divisor magic
        const int k  = jk - j * SS;
        const int xs = (k * L2) / SS;
        const int ex = ((k + 1) * L2 + 6) / SS - xs;     // 1..3
        const uint4* pp = &P[j * 104 + xs * 8 + c8];
        uint4 m = pp[0];
        if (ex > 1) m = pkmax4(m, pp[8]);
        if (ex > 2) m = pkmax4(m, pp[16]);

        float* o = &obuf[jk * 68 + c8 * 8];
        __half2 h;
        h = *(const __half2*)&m.x; o[0] = __half2float(h.x); o[1] = __half2float(h.y);
        h = *(const __half2*)&m.y; o[2] = __half2float(h.x); o[3] = __half2float(h.y);
        h = *(const __half2*)&m.z; o[4] = __half2float(h.x); o[5] = __half2float(h.y);
        h = *(const __half2*)&m.w; o[6] = __half2float(h.x); o[7] = __half2float(h.y);
    }
    __syncthreads();

    // ---- phase C: coalesced write-out (49-float runs per channel) ----
    float* op = out + (size_t)n * CC * (SS * SS * SS) + (size_t)i * 49;
    for (int idx = t; idx < 49 * CC; idx += 256) {
        const int c = idx / 49;                 // const-divisor magic
        const int q = idx - c * 49;
        op[(size_t)c * 343 + q] = obuf[q * 68 + c];
    }
}

// ---------------- fallback: round-0 thread-per-bin (proven) --------
__global__ __launch_bounds__(256) void croproi_fallback(
    const float* __restrict__ f, const float* __restrict__ props,
    float* __restrict__ out, int total)
{
    int tid = blockIdx.x * blockDim.x + threadIdx.x;
    if (tid >= total) return;
    int k = tid % SS;
    int t = tid / SS;
    int j = t % SS; t /= SS;
    int i = t % SS; t /= SS;
    int c = t % CC;
    int n = t / CC;
    const float* p = props + n * 8;
    int b = (int)p[0];
    int lo0, lo1, lo2, L0, L1, L2;
    {
        float c0f = p[2] - 0.5f * p[5]; float c1f = c0f + p[5];
        int lo = (int)floorf(c0f * INV_SCALE); if (lo < 0) lo = 0;
        int hi = (int)ceilf (c1f * INV_SCALE); if (hi > DP) hi = DP;
        lo0 = lo; L0 = hi - lo;
        c0f = p[3] - 0.5f * p[6]; c1f = c0f + p[6];
        lo = (int)floorf(c0f * INV_SCALE); if (lo < 0) lo = 0;
        hi = (int)ceilf (c1f * INV_SCALE); if (hi > DP) hi = DP;
        lo1 = lo; L1 = hi - lo;
        c0f = p[4] - 0.5f * p[7]; c1f = c0f + p[7];
        lo = (int)floorf(c0f * INV_SCALE); if (lo < 0) lo = 0;
        hi = (int)ceilf (c1f * INV_SCALE); if (hi > DP) hi = DP;
        lo2 = lo; L2 = hi - lo;
    }
    int zs = lo0 + (i * L0) / SS, ze = lo0 + ((i + 1) * L0 + SS - 1) / SS;
    int ys = lo1 + (j * L1) / SS, ye = lo1 + ((j + 1) * L1 + SS - 1) / SS;
    int xs = lo2 + (k * L2) / SS, xe = lo2 + ((k + 1) * L2 + SS - 1) / SS;
    const float* fb = f + (size_t)(b * CC + c) * VOL;
    float m = -INFINITY;
    for (int z = zs; z < ze; ++z)
        for (int y = ys; y < ye; ++y) {
            const float* row = fb + (z * DP + y) * DP;
            for (int x = xs; x < xe; ++x) m = fmaxf(m, row[x]);
        }
    out[tid] = m;
}

extern "C" void kernel_launch(void* const* d_in, const int* in_sizes, int n_in,
                              void* d_out, int out_size, void* d_ws, size_t ws_size,
                              hipStream_t stream) {
    const float* f     = (const float*)d_in[0];
    const float* props = (const float*)d_in[2];
    float* out = (float*)d_out;

    const int B = in_sizes[0] / (CC * VOL);   // 4
    const int N = in_sizes[2] / 8;            // 96

    const size_t ft_bytes = (size_t)B * VOL * CC * sizeof(__half);
    if (ws_size >= ft_bytes) {
        __half* ft = (__half*)d_ws;
        dim3 g1(VOL / 64, B);                 // 216 x 4 = 864 blocks
        transpose_cl<<<g1, 256, 0, stream>>>(f, (uint4*)ft);
        dim3 g2(N, SS);                       // 96 x 7 = 672 blocks
        croproi_stream<<<g2, 256, 0, stream>>>(ft, props, out);
    } else {
        int total = N * CC * SS * SS * SS;
        croproi_fallback<<<(total + 255) / 256, 256, 0, stream>>>(f, props, out, total);
    }
}

// Round 16
// 17.219 us; speedup vs baseline: 9.0033x; 1.0762x over previous
//
#include <hip/hip_runtime.h>
#include <hip/hip_fp16.h>

// CropRoi: 3D adaptive max-pool over per-proposal crop boxes.
// f:        [B=4, C=64, 24, 24, 24] f32
// proposals:[N, 8] f32 = [b, score, cx, cy, cz, sx, sy, sz]
// out:      [N, C, 7, 7, 7] f32
//
// r15: occupancy/latency fixes on the proven two-kernel pipeline.
// K1: 1728 blocks (32-spatial x 64-ch tile): 2 float4 loads + 1 uint4 store
//     per thread (was 864 blocks, 4+2) -> 2x blocks, half the serial chain.
// K2: streaming separable pool (r14) j-SPLIT over grid.z=2 -> 1344 blocks
//     (5.25/CU, 21 waves/CU = r11's proven TLP regime). Phase A keeps
//     contiguous 1KB wave-loads of full 128B points; (n,i,0)/(n,i,1) are
//     672 blocks apart = same XCD -> shared L2 lines.
//
// History: r9 grid.sync / r12 pc-flag 100-155us (intra-dispatch cross-XCD
// sync dead); r13 direct 52.8us (serial LDS chains dead); r10 672-block
// gather regressed (low-TLP latency); r8 predication -3.1us.
// Precision: fp16 RTN on ~N(0,1); absmax 0.03125 << 0.099.

#define SS 7
#define CC 64
#define DP 24
#define DP2 (DP*DP)        // 576
#define VOL (DP*DP*DP)     // 13824
#define INV_SCALE 0.25f
#define NEGINF2 0xFC00FC00u

static __device__ __forceinline__ unsigned pkmax(unsigned a, unsigned b) {
    unsigned r;
    asm("v_pk_max_f16 %0, %1, %2" : "=v"(r) : "v"(a), "v"(b));
    return r;
}
static __device__ __forceinline__ uint4 pkmax4(uint4 a, uint4 b) {
    uint4 r;
    r.x = pkmax(a.x, b.x); r.y = pkmax(a.y, b.y);
    r.z = pkmax(a.z, b.z); r.w = pkmax(a.w, b.w);
    return r;
}

// ---------------- kernel 1: channel-last transpose to fp16 ----------------
// 32-spatial x 64-channel tile; 1728 blocks.
__global__ __launch_bounds__(256) void transpose_cl(
    const float* __restrict__ f,   // [B][CC][VOL] f32
    uint4* __restrict__ ft4)       // [B][VOL][CC/8]
{
    __shared__ float tile[64][33];     // 8448 B
    const int b  = blockIdx.y;
    const int s0 = blockIdx.x * 32;
    const int t  = threadIdx.x;
    const int x4 = (t & 7) * 4;        // spatial quad within tile
    const int rr = t >> 3;             // 0..31
    #pragma unroll
    for (int it = 0; it < 2; ++it) {
        const int r = it * 32 + rr;    // channel
        const float4 v = *(const float4*)&f[(size_t)(b * CC + r) * VOL + s0 + x4];
        tile[r][x4 + 0] = v.x; tile[r][x4 + 1] = v.y;
        tile[r][x4 + 2] = v.z; tile[r][x4 + 3] = v.w;
    }
    __syncthreads();
    const int s  = t >> 3;             // spatial within tile (0..31)
    const int c8 = (t & 7) * 8;        // channel octet
    __half h[8];
    #pragma unroll
    for (int u = 0; u < 8; ++u)
        h[u] = __float2half(tile[c8 + u][s]);   // 2-way bank alias: free
    ft4[((size_t)b * VOL + s0 + s) * (CC / 8) + (c8 >> 3)] = *(uint4*)h;
}

// ---------------- kernel 2: streaming separable pool, j-split ----------------
__global__ __launch_bounds__(256) void croproi_stream(
    const __half* __restrict__ ft,    // [B][VOL][CC] fp16
    const float* __restrict__ props,  // [N][8]
    float* __restrict__ out)          // [N][CC][343] f32
{
    __shared__ uint4 P[4 * 104];      // [j_local][x(13)][c8(8)]  6656 B
    __shared__ float obuf[28 * 68];   // 7616 B
    const int n  = blockIdx.x;
    const int i  = blockIdx.y;        // z-bin slice
    const int zc = blockIdx.z;        // j-half: 0 -> j 0..3, 1 -> j 4..6
    const int t  = threadIdx.x;

    // ---- box decode (wave-uniform -> SGPR) ----
    const float* p = props + (size_t)n * 8;
    int b = (int)p[0];
    int lo0, lo1, lo2, L0, L1, L2;
    {
        float c0f = p[2] - 0.5f * p[5];
        float c1f = c0f + p[5];
        int lo = (int)floorf(c0f * INV_SCALE); if (lo < 0) lo = 0;
        int hi = (int)ceilf (c1f * INV_SCALE); if (hi > DP) hi = DP;
        lo0 = lo; L0 = hi - lo;

        c0f = p[3] - 0.5f * p[6];
        c1f = c0f + p[6];
        lo = (int)floorf(c0f * INV_SCALE); if (lo < 0) lo = 0;
        hi = (int)ceilf (c1f * INV_SCALE); if (hi > DP) hi = DP;
        lo1 = lo; L1 = hi - lo;

        c0f = p[4] - 0.5f * p[7];
        c1f = c0f + p[7];
        lo = (int)floorf(c0f * INV_SCALE); if (lo < 0) lo = 0;
        hi = (int)ceilf (c1f * INV_SCALE); if (hi > DP) hi = DP;
        lo2 = lo; L2 = hi - lo;
    }
    b   = __builtin_amdgcn_readfirstlane(b);
    lo0 = __builtin_amdgcn_readfirstlane(lo0);
    lo1 = __builtin_amdgcn_readfirstlane(lo1);
    lo2 = __builtin_amdgcn_readfirstlane(lo2);
    L0  = __builtin_amdgcn_readfirstlane(L0);
    L1  = __builtin_amdgcn_readfirstlane(L1);
    L2  = __builtin_amdgcn_readfirstlane(L2);

    const int zs = (i * L0) / SS;
    const int ez = ((i + 1) * L0 + 6) / SS - zs;        // 1..3 (uniform)
    const int jlo = zc ? 4 : 0;
    const int nj  = zc ? 3 : 4;

    // base at (b, lo0+zs, lo1, lo2), channel 0, in uint4 units (8/point)
    const uint4* base0 = (const uint4*)ft
        + ((size_t)b * VOL + (size_t)(lo0 + zs) * DP2
           + (size_t)lo1 * DP + lo2) * 8;

    // ---- phase A: zy-pool streaming loads -> P[j_local][x][c8] ----
    // units: nj * 13x * 8c8 (<=416); lanes sweep c8 then x -> contiguous
    const int unitsA = nj * 104;
    for (int u = t; u < unitsA; u += 256) {
        const int jl = u / 104;                 // const-divisor magic
        const int r  = u - jl * 104;
        const int x  = r >> 3;
        const int c8 = r & 7;
        const int j  = jlo + jl;
        const int ys = (j * L1) / SS;
        const int ey = ((j + 1) * L1 + 6) / SS - ys;     // 1..3
        const bool act = (x < L2);

        const uint4* bp = base0 + (ys * DP + x) * 8 + c8;
        uint4 m; m.x = m.y = m.z = m.w = NEGINF2;
        #pragma unroll
        for (int zi = 0; zi < 3; ++zi) {
            if (zi < ez) {                      // wave-uniform branch
                const uint4* bz = bp + zi * (DP2 * 8);
                uint4 v0, v1, v2;
                v0.x = v0.y = v0.z = v0.w = NEGINF2; v1 = v0; v2 = v0;
                if (act)           v0 = bz[0];           // exec-masked
                if (act && ey > 1) v1 = bz[DP * 8];
                if (act && ey > 2) v2 = bz[2 * DP * 8];
                m = pkmax4(m, pkmax4(pkmax4(v0, v1), v2));
            }
        }
        if (act) P[jl * 104 + x * 8 + c8] = m;
    }
    __syncthreads();

    // ---- phase B: x-pool from P -> obuf f32 ----
    const int unitsB = nj * 56;                 // (nj*7 bins) * 8 c8
    if (t < unitsB) {
        const int jkl = t >> 3;                 // local bin (j_local*7 + k)
        const int c8  = t & 7;
        const int jl  = jkl / SS;               // const-divisor magic
        const int k   = jkl - jl * SS;
        const int xs  = (k * L2) / SS;
        const int ex  = ((k + 1) * L2 + 6) / SS - xs;    // 1..3
        const uint4* pp = &P[jl * 104 + xs * 8 + c8];
        uint4 m = pp[0];
        if (ex > 1) m = pkmax4(m, pp[8]);
        if (ex > 2) m = pkmax4(m, pp[16]);

        float* o = &obuf[jkl * 68 + c8 * 8];
        __half2 h;
        h = *(const __half2*)&m.x; o[0] = __half2float(h.x); o[1] = __half2float(h.y);
        h = *(const __half2*)&m.y; o[2] = __half2float(h.x); o[3] = __half2float(h.y);
        h = *(const __half2*)&m.z; o[4] = __half2float(h.x); o[5] = __half2float(h.y);
        h = *(const __half2*)&m.w; o[6] = __half2float(h.x); o[7] = __half2float(h.y);
    }
    __syncthreads();

    // ---- phase C: coalesced write-out (28/21-float runs per channel) ----
    float* op = out + (size_t)n * CC * (SS * SS * SS) + (size_t)i * 49 + jlo * SS;
    if (zc == 0) {
        for (int idx = t; idx < 28 * CC; idx += 256) {
            const int c = idx / 28;             // const-divisor magic
            const int q = idx - c * 28;
            op[(size_t)c * 343 + q] = obuf[q * 68 + c];
        }
    } else {
        for (int idx = t; idx < 21 * CC; idx += 256) {
            const int c = idx / 21;             // const-divisor magic
            const int q = idx - c * 21;
            op[(size_t)c * 343 + q] = obuf[q * 68 + c];
        }
    }
}

// ---------------- fallback: round-0 thread-per-bin (proven) --------
__global__ __launch_bounds__(256) void croproi_fallback(
    const float* __restrict__ f, const float* __restrict__ props,
    float* __restrict__ out, int total)
{
    int tid = blockIdx.x * blockDim.x + threadIdx.x;
    if (tid >= total) return;
    int k = tid % SS;
    int t = tid / SS;
    int j = t % SS; t /= SS;
    int i = t % SS; t /= SS;
    int c = t % CC;
    int n = t / CC;
    const float* p = props + n * 8;
    int b = (int)p[0];
    int lo0, lo1, lo2, L0, L1, L2;
    {
        float c0f = p[2] - 0.5f * p[5]; float c1f = c0f + p[5];
        int lo = (int)floorf(c0f * INV_SCALE); if (lo < 0) lo = 0;
        int hi = (int)ceilf (c1f * INV_SCALE); if (hi > DP) hi = DP;
        lo0 = lo; L0 = hi - lo;
        c0f = p[3] - 0.5f * p[6]; c1f = c0f + p[6];
        lo = (int)floorf(c0f * INV_SCALE); if (lo < 0) lo = 0;
        hi = (int)ceilf (c1f * INV_SCALE); if (hi > DP) hi = DP;
        lo1 = lo; L1 = hi - lo;
        c0f = p[4] - 0.5f * p[7]; c1f = c0f + p[7];
        lo = (int)floorf(c0f * INV_SCALE); if (lo < 0) lo = 0;
        hi = (int)ceilf (c1f * INV_SCALE); if (hi > DP) hi = DP;
        lo2 = lo; L2 = hi - lo;
    }
    int zs = lo0 + (i * L0) / SS, ze = lo0 + ((i + 1) * L0 + SS - 1) / SS;
    int ys = lo1 + (j * L1) / SS, ye = lo1 + ((j + 1) * L1 + SS - 1) / SS;
    int xs = lo2 + (k * L2) / SS, xe = lo2 + ((k + 1) * L2 + SS - 1) / SS;
    const float* fb = f + (size_t)(b * CC + c) * VOL;
    float m = -INFINITY;
    for (int z = zs; z < ze; ++z)
        for (int y = ys; y < ye; ++y) {
            const float* row = fb + (z * DP + y) * DP;
            for (int x = xs; x < xe; ++x) m = fmaxf(m, row[x]);
        }
    out[tid] = m;
}

extern "C" void kernel_launch(void* const* d_in, const int* in_sizes, int n_in,
                              void* d_out, int out_size, void* d_ws, size_t ws_size,
                              hipStream_t stream) {
    const float* f     = (const float*)d_in[0];
    const float* props = (const float*)d_in[2];
    float* out = (float*)d_out;

    const int B = in_sizes[0] / (CC * VOL);   // 4
    const int N = in_sizes[2] / 8;            // 96

    const size_t ft_bytes = (size_t)B * VOL * CC * sizeof(__half);
    if (ws_size >= ft_bytes) {
        __half* ft = (__half*)d_ws;
        dim3 g1(VOL / 32, B);                 // 432 x 4 = 1728 blocks
        transpose_cl<<<g1, 256, 0, stream>>>(f, (uint4*)ft);
        dim3 g2(N, SS, 2);                    // 96 x 7 x 2 = 1344 blocks
        croproi_stream<<<g2, 256, 0, stream>>>(ft, props, out);
    } else {
        int total = N * CC * SS * SS * SS;
        croproi_fallback<<<(total + 255) / 256, 256, 0, stream>>>(f, props, out, total);
    }
}